// Round 1
// baseline (586.050 us; speedup 1.0000x reference)
//
#include <hip/hip_runtime.h>
#include <hip/hip_bf16.h>

// Problem constants (match reference)
#define BB 256
#define II 182
#define TT 2000
#define OO 2

// Kernel 1: curr[b][o][t] = sum_i inputs[b][i][t] * W[o][i] + bias[o]
// inputs layout [B, I, T] (t contiguous). Each thread handles 4 consecutive t
// via float4 loads; consecutive lanes -> consecutive t -> 1 KiB coalesced per
// wave per i-iteration. W (2x182 floats) staged in LDS.
__global__ __launch_bounds__(256) void curr_kernel(const float* __restrict__ in,
                                                   const float* __restrict__ W,
                                                   const float* __restrict__ bias,
                                                   float* __restrict__ curr) {
    __shared__ float w0[II];
    __shared__ float w1[II];
    for (int i = threadIdx.x; i < II; i += blockDim.x) {
        w0[i] = W[i];        // W[0][i]
        w1[i] = W[II + i];   // W[1][i]
    }
    __syncthreads();

    const int b = blockIdx.x >> 1;                              // 2 blocks per batch
    const int g = (blockIdx.x & 1) * blockDim.x + threadIdx.x;  // t-group (4 t's each)
    if (g >= TT / 4) return;
    const int t = g * 4;

    const float4* p = (const float4*)(in + (size_t)b * II * TT + t);
    const int stride4 = TT / 4;  // float4 stride between consecutive i

    float4 acc0 = {0.f, 0.f, 0.f, 0.f};
    float4 acc1 = {0.f, 0.f, 0.f, 0.f};

#pragma unroll 2
    for (int i = 0; i < II; ++i) {
        const float4 x = p[(size_t)i * stride4];
        const float a = w0[i];
        const float c = w1[i];
        acc0.x += x.x * a; acc0.y += x.y * a; acc0.z += x.z * a; acc0.w += x.w * a;
        acc1.x += x.x * c; acc1.y += x.y * c; acc1.z += x.z * c; acc1.w += x.w * c;
    }

    const float b0 = bias[0];
    const float b1 = bias[1];
    acc0.x += b0; acc0.y += b0; acc0.z += b0; acc0.w += b0;
    acc1.x += b1; acc1.y += b1; acc1.z += b1; acc1.w += b1;

    float4* c0 = (float4*)(curr + ((size_t)b * OO + 0) * TT + t);
    float4* c1 = (float4*)(curr + ((size_t)b * OO + 1) * TT + t);
    *c0 = acc0;
    *c1 = acc1;
}

// Kernel 2: per-(b,o) linear recurrence over t.
//   syn_t = a*syn_{t-1} + curr_t ; mem_t = bt*mem_{t-1} + syn_t
// out[b][t][o] = mem_t. 512 independent scans, one thread each.
__global__ __launch_bounds__(64) void scan_kernel(const float* __restrict__ curr,
                                                  const float* __restrict__ alpha,
                                                  const float* __restrict__ beta,
                                                  float* __restrict__ out) {
    const int gid = blockIdx.x * 64 + threadIdx.x;
    if (gid >= BB * OO) return;
    const int b = gid >> 1;
    const int o = gid & 1;

    const float a  = fminf(fmaxf(alpha[o], 0.f), 1.f);
    const float bt = fminf(fmaxf(beta[o],  0.f), 1.f);

    const float4* c4 = (const float4*)(curr + ((size_t)b * OO + o) * TT);
    float* op = out + (size_t)b * TT * OO + o;

    float syn = 0.f, mem = 0.f;
    for (int t4 = 0; t4 < TT / 4; ++t4) {
        const float4 x = c4[t4];
        const int tb = t4 * 4;
        syn = a * syn + x.x; mem = bt * mem + syn; op[(tb + 0) * OO] = mem;
        syn = a * syn + x.y; mem = bt * mem + syn; op[(tb + 1) * OO] = mem;
        syn = a * syn + x.z; mem = bt * mem + syn; op[(tb + 2) * OO] = mem;
        syn = a * syn + x.w; mem = bt * mem + syn; op[(tb + 3) * OO] = mem;
    }
}

extern "C" void kernel_launch(void* const* d_in, const int* in_sizes, int n_in,
                              void* d_out, int out_size, void* d_ws, size_t ws_size,
                              hipStream_t stream) {
    const float* inputs = (const float*)d_in[0];  // [B, I, T]
    const float* W      = (const float*)d_in[1];  // [O, I]
    const float* bias   = (const float*)d_in[2];  // [O]
    const float* alpha  = (const float*)d_in[3];  // [O]
    const float* beta   = (const float*)d_in[4];  // [O]
    float* out = (float*)d_out;                   // [B, T, O]
    float* curr = (float*)d_ws;                   // [B, O, T] staging (4.096 MB)

    // Kernel 1: 2 blocks per batch x 256 threads (each 4 t's) covers T=2000.
    curr_kernel<<<BB * 2, 256, 0, stream>>>(inputs, W, bias, curr);

    // Kernel 2: 512 scans, 8 blocks of 64 to spread across CUs.
    scan_kernel<<<(BB * OO + 63) / 64, 64, 0, stream>>>(curr, alpha, beta, out);
}

// Round 2
// 512.998 us; speedup vs baseline: 1.1424x; 1.1424x over previous
//
#include <hip/hip_runtime.h>
#include <hip/hip_bf16.h>

// Problem constants (match reference)
#define BB 256
#define II 182
#define TT 2000
#define OO 2

// Fused kernel: one block per batch element b.
//   Phase 1: curr[o][t] = sum_i in[b][i][t] * W[o][i] + bias[o]  -> LDS
//   Phase 2: serial linear scan over t for o=0,1 (2 lanes)        -> LDS
//   Phase 3: cooperative coalesced float4 store of out[b][:][:]
// 512 threads = 8 waves/CU; unroll 7 gives 7 outstanding 16B loads/wave
// (~14 MB chip-wide in flight > ~5.7 MB BW*latency product) -> HBM-bound.
__global__ __launch_bounds__(512) void snn_fused_kernel(const float* __restrict__ in,
                                                        const float* __restrict__ W,
                                                        const float* __restrict__ bias,
                                                        const float* __restrict__ alpha,
                                                        const float* __restrict__ beta,
                                                        float* __restrict__ out) {
    __shared__ float w0[II];
    __shared__ float w1[II];
    __shared__ float curr_s[OO][TT];   // [o][t], 16 KB
    __shared__ float mem_s[TT * OO];   // [t][o], 16 KB

    const int b = blockIdx.x;
    const int tid = threadIdx.x;

    if (tid < II) {
        w0[tid] = W[tid];       // W[0][i]
        w1[tid] = W[II + tid];  // W[1][i]
    }
    __syncthreads();

    // ---- Phase 1: GEMM into LDS ----
    if (tid < TT / 4) {  // 500 active threads, each one float4 (4 consecutive t)
        const float4* p = (const float4*)(in + (size_t)b * II * TT) + tid;
        float4 a0 = {0.f, 0.f, 0.f, 0.f};
        float4 a1 = {0.f, 0.f, 0.f, 0.f};
#pragma unroll 7
        for (int i = 0; i < II; ++i) {
            const float4 x = p[i * (TT / 4)];
            const float wa = w0[i];
            const float wb = w1[i];
            a0.x += x.x * wa; a0.y += x.y * wa; a0.z += x.z * wa; a0.w += x.w * wa;
            a1.x += x.x * wb; a1.y += x.y * wb; a1.z += x.z * wb; a1.w += x.w * wb;
        }
        const float b0 = bias[0];
        const float b1 = bias[1];
        const int t = tid * 4;
        curr_s[0][t + 0] = a0.x + b0; curr_s[0][t + 1] = a0.y + b0;
        curr_s[0][t + 2] = a0.z + b0; curr_s[0][t + 3] = a0.w + b0;
        curr_s[1][t + 0] = a1.x + b1; curr_s[1][t + 1] = a1.y + b1;
        curr_s[1][t + 2] = a1.z + b1; curr_s[1][t + 3] = a1.w + b1;
    }
    __syncthreads();

    // ---- Phase 2: serial scan, one lane per o (syn & mem chains overlap at 4cyc/t) ----
    if (tid < OO) {
        const int o = tid;
        const float a  = fminf(fmaxf(alpha[o], 0.f), 1.f);
        const float bt = fminf(fmaxf(beta[o],  0.f), 1.f);
        const float4* c4 = (const float4*)curr_s[o];
        float syn = 0.f, mem = 0.f;
        for (int t4 = 0; t4 < TT / 4; ++t4) {
            const float4 x = c4[t4];
            const int t = t4 * 4;
            syn = a * syn + x.x; mem = bt * mem + syn; mem_s[(t + 0) * OO + o] = mem;
            syn = a * syn + x.y; mem = bt * mem + syn; mem_s[(t + 1) * OO + o] = mem;
            syn = a * syn + x.z; mem = bt * mem + syn; mem_s[(t + 2) * OO + o] = mem;
            syn = a * syn + x.w; mem = bt * mem + syn; mem_s[(t + 3) * OO + o] = mem;
        }
    }
    __syncthreads();

    // ---- Phase 3: coalesced store of out[b][t][o] (4000 floats = 1000 float4) ----
    float4* o4 = (float4*)(out + (size_t)b * TT * OO);
    const float4* m4 = (const float4*)mem_s;
#pragma unroll
    for (int idx = tid; idx < TT * OO / 4; idx += 512) {
        o4[idx] = m4[idx];
    }
}

extern "C" void kernel_launch(void* const* d_in, const int* in_sizes, int n_in,
                              void* d_out, int out_size, void* d_ws, size_t ws_size,
                              hipStream_t stream) {
    const float* inputs = (const float*)d_in[0];  // [B, I, T]
    const float* W      = (const float*)d_in[1];  // [O, I]
    const float* bias   = (const float*)d_in[2];  // [O]
    const float* alpha  = (const float*)d_in[3];  // [O]
    const float* beta   = (const float*)d_in[4];  // [O]
    float* out = (float*)d_out;                   // [B, T, O]

    snn_fused_kernel<<<BB, 512, 0, stream>>>(inputs, W, bias, alpha, beta, out);
}